// Round 1
// baseline (1909.470 us; speedup 1.0000x reference)
//
#include <hip/hip_runtime.h>
#include <math.h>

#define NR 4096
#define UD 64
#define BD 256
#define SD 256
#define RD 512
#define UBD 16384
#define DECAY 0.99f

// output offsets (in floats), concatenated in reference return order
#define OFF_MDR   0ull          // memory_delta_rule   [4096,512]
#define OFF_MSIG  2097152ull    // memory_signature    [4096,256]
#define OFF_MCONF 3145728ull    // memory_conf         [4096,1]
#define OFF_NDP   3149824ull    // new_delta_proto     [64,256,512]
#define OFF_NSP   11538432ull   // new_signature_proto [64,256,256]
#define OFF_NEC   15732736ull   // new_ema_conf        [64,256]
#define OFF_NUS   15749120ull   // new_usage           [64,256]
#define OFF_SCAL  15765504ull   // write_rate, usage_fraction, usage_entropy

// ---------------------------------------------------------------------------
// Detect how write_mask (jax bool) was delivered: int32 (2), float32 (1), byte (0)
__global__ void detect_mask_kernel(const unsigned char* __restrict__ wm,
                                   int* __restrict__ flag)
{
  if (threadIdx.x != 0 || blockIdx.x != 0) return;
  const int*   wi = (const int*)wm;
  const float* wf = (const float*)wm;
  bool is_i32 = true, is_f32 = true;
  for (int i = 0; i < 16; ++i) {
    int v = wi[i];
    if (v != 0 && v != 1) is_i32 = false;
    float f = wf[i];
    if (f != 0.f && f != 1.f) is_f32 = false;
  }
  *flag = is_i32 ? 2 : (is_f32 ? 1 : 0);
}

// ---------------------------------------------------------------------------
// Per-row: denom, unnormalized base_conf, argmax(q_u), argmax(q_b), wgt, cell, m
__global__ __launch_bounds__(256) void row_prep_kernel(
    const float* __restrict__ q_u, const float* __restrict__ q_b,
    const float* __restrict__ usage, const float* __restrict__ ema,
    const unsigned char* __restrict__ wm, const int* __restrict__ flag,
    float* __restrict__ denom, float* __restrict__ base_raw,
    float* __restrict__ wgt, int* __restrict__ cellid, float* __restrict__ mrow)
{
  const int n = blockIdx.x;
  const int t = threadIdx.x;
  __shared__ float s_qu[UD];
  __shared__ float r1[256];
  __shared__ float r2[256];
  __shared__ int   ri[256];
  if (t < UD) s_qu[t] = q_u[(size_t)n * UD + t];
  __syncthreads();
  const float qb = q_b[(size_t)n * BD + t];
  float accd = 0.f, accc = 0.f;
  #pragma unroll 4
  for (int u = 0; u < UD; ++u) {
    const int idx = u * BD + t;
    if (usage[idx] > 0.f) {
      const float qu = s_qu[u];
      accd += qu;
      accc += qu * ema[idx];
    }
  }
  accd *= qb; accc *= qb;
  r1[t] = accd; r2[t] = accc;
  __syncthreads();
  for (int s = 128; s > 0; s >>= 1) {
    if (t < s) { r1[t] += r1[t + s]; r2[t] += r2[t + s]; }
    __syncthreads();
  }
  const float dsum = r1[0];
  const float csum = r2[0];
  __syncthreads();
  // argmax over q_b (first-index tie-break)
  r1[t] = qb; ri[t] = t;
  __syncthreads();
  for (int s = 128; s > 0; s >>= 1) {
    if (t < s) {
      float v2 = r1[t + s]; int i2 = ri[t + s];
      if (v2 > r1[t] || (v2 == r1[t] && i2 < ri[t])) { r1[t] = v2; ri[t] = i2; }
    }
    __syncthreads();
  }
  const float bmax = r1[0]; const int bidx = ri[0];
  __syncthreads();
  // argmax over q_u
  r1[t] = (t < UD) ? s_qu[t] : -1e30f; ri[t] = t;
  __syncthreads();
  for (int s = 128; s > 0; s >>= 1) {
    if (t < s) {
      float v2 = r1[t + s]; int i2 = ri[t + s];
      if (v2 > r1[t] || (v2 == r1[t] && i2 < ri[t])) { r1[t] = v2; ri[t] = i2; }
    }
    __syncthreads();
  }
  if (t == 0) {
    const float umax = r1[0]; const int uidx = ri[0];
    const int fm = *flag;
    float m;
    if (fm == 2)      m = (((const int*)wm)[n]   != 0)   ? 1.f : 0.f;
    else if (fm == 1) m = (((const float*)wm)[n] != 0.f) ? 1.f : 0.f;
    else              m = (wm[n] != 0) ? 1.f : 0.f;
    denom[n]    = dsum;
    base_raw[n] = csum;
    wgt[n]      = umax * bmax * m;
    cellid[n]   = uidx * BD + bidx;
    mrow[n]     = m;
  }
}

// ---------------------------------------------------------------------------
// Retrieve GEMM: out[n,r] = (1/denom[n]) * sum_ub q_u[n,u] q_b[n,b] valid[ub] proto[ub,r]
// A generated on the fly; one 32-wide k-chunk has constant u (since B=256).
#define TM 64
#define TN 64
#define KB 32

__global__ __launch_bounds__(256) void retrieve_gemm_kernel(
    const float* __restrict__ q_u, const float* __restrict__ q_b,
    const float* __restrict__ usage,
    const float* __restrict__ dproto, const float* __restrict__ sproto,
    const float* __restrict__ denom, float* __restrict__ out)
{
  __shared__ float sA[KB][TM];   // k-major (transposed) for float4 fragment reads
  __shared__ float sB[KB][TN];
  const int bx = blockIdx.x;     // 64 row tiles
  const int by = blockIdx.y;     // 0..7 delta cols, 8..11 signature cols
  const int n0 = bx * TM;
  const float* Bsrc; int ldB; int col0; float* outp; int ldO;
  if (by < 8) { Bsrc = dproto; ldB = RD; col0 = by * TN;       outp = out + OFF_MDR;  ldO = RD; }
  else        { Bsrc = sproto; ldB = SD; col0 = (by - 8) * TN; outp = out + OFF_MSIG; ldO = SD; }
  const int tid = threadIdx.x;
  const int tx = tid & 15;
  const int ty = tid >> 4;
  const int kr = tid >> 4;           // B-tile load row 0..15
  const int bc = (tid & 15) * 4;     // B-tile load col
  const int arow = tid >> 2;         // A-gen row 0..63
  const int ak0 = (tid & 3) * 8;     // A-gen k chunk 0,8,16,24
  float acc[4][4] = {{0.f}};
  for (int k0 = 0; k0 < UBD; k0 += KB) {
    const int u  = k0 >> 8;
    const int b0 = k0 & 255;
    // load B tile 32x64 (coalesced float4)
    {
      const float* src = Bsrc + (size_t)(k0 + kr) * ldB + col0 + bc;
      const float4 v0 = *(const float4*)src;
      const float4 v1 = *(const float4*)(src + (size_t)16 * ldB);
      *(float4*)&sB[kr][bc]      = v0;
      *(float4*)&sB[kr + 16][bc] = v1;
    }
    // generate A tile (transposed): A[kk][row] = q_u[row,u]*q_b[row,b0+kk]*valid[u,b0+kk]
    {
      const float qu  = q_u[(size_t)(n0 + arow) * UD + u];
      const float* qbp = q_b + (size_t)(n0 + arow) * BD + b0 + ak0;
      const float* usp = usage + u * BD + b0 + ak0;
      #pragma unroll
      for (int j = 0; j < 8; ++j) {
        const float a = (usp[j] > 0.f) ? qu * qbp[j] : 0.f;
        sA[ak0 + j][arow] = a;
      }
    }
    __syncthreads();
    #pragma unroll
    for (int kk = 0; kk < KB; ++kk) {
      const float4 a4 = *(const float4*)&sA[kk][ty * 4];
      const float4 b4 = *(const float4*)&sB[kk][tx * 4];
      const float a[4] = {a4.x, a4.y, a4.z, a4.w};
      const float b[4] = {b4.x, b4.y, b4.z, b4.w};
      #pragma unroll
      for (int i = 0; i < 4; ++i)
        #pragma unroll
        for (int j = 0; j < 4; ++j)
          acc[i][j] += a[i] * b[j];
    }
    __syncthreads();
  }
  #pragma unroll
  for (int i = 0; i < 4; ++i) {
    const int n = n0 + ty * 4 + i;
    const float d = denom[n];
    const float scale = (d > 0.f) ? (1.f / fmaxf(d, 1e-6f)) : 0.f;
    float4 v;
    v.x = acc[i][0] * scale; v.y = acc[i][1] * scale;
    v.z = acc[i][2] * scale; v.w = acc[i][3] * scale;
    *(float4*)&outp[(size_t)n * ldO + col0 + tx * 4] = v;
  }
}

// ---------------------------------------------------------------------------
// memory_conf: cosine(q_sigma, memory_signature + 1e-6), base_conf, clip
__global__ __launch_bounds__(256) void conf_kernel(
    const float* __restrict__ q_sigma, const float* __restrict__ out,
    const float* __restrict__ denom, const float* __restrict__ base_raw,
    float* __restrict__ mconf)
{
  const int n = blockIdx.x;
  const int t = threadIdx.x;
  __shared__ float r1[256], r2[256], r3[256];
  const float a = q_sigma[(size_t)n * SD + t];
  const float b = out[OFF_MSIG + (size_t)n * SD + t] + 1e-6f;
  r1[t] = a * a; r2[t] = b * b; r3[t] = a * b;
  __syncthreads();
  for (int s = 128; s > 0; s >>= 1) {
    if (t < s) { r1[t] += r1[t + s]; r2[t] += r2[t + s]; r3[t] += r3[t + s]; }
    __syncthreads();
  }
  if (t == 0) {
    const float na = fmaxf(sqrtf(r1[0]), 1e-12f);
    const float nb = fmaxf(sqrtf(r2[0]), 1e-12f);
    const float cosv = r3[0] / (na * nb);
    const float agree = 0.5f * (1.f + cosv);
    const float d = denom[n];
    const float base = (d > 0.f) ? base_raw[n] / fmaxf(d, 1e-6f) : 0.f;
    mconf[n] = fminf(fmaxf(base * agree, 0.f), 1.f);
  }
}

// ---------------------------------------------------------------------------
// Scatter segment-sums into the (zeroed) new_*_proto output regions + sum_w/cnt
__global__ __launch_bounds__(256) void scatter_kernel(
    const float* __restrict__ dtarget, const float* __restrict__ q_sigma,
    const float* __restrict__ wgt, const int* __restrict__ cellid,
    const float* __restrict__ mrow,
    float* __restrict__ sumd, float* __restrict__ sums,
    float* __restrict__ sum_w, float* __restrict__ cnt)
{
  const int n = blockIdx.x;
  if (mrow[n] == 0.f) return;
  const int t = threadIdx.x;
  const int c = cellid[n];
  const float w = wgt[n];
  atomicAdd(&sumd[(size_t)c * RD + t],       dtarget[(size_t)n * RD + t] * w);
  atomicAdd(&sumd[(size_t)c * RD + t + 256], dtarget[(size_t)n * RD + t + 256] * w);
  atomicAdd(&sums[(size_t)c * SD + t],       q_sigma[(size_t)n * SD + t] * w);
  if (t == 0) { atomicAdd(&sum_w[c], w); atomicAdd(&cnt[c], 1.f); }
}

// ---------------------------------------------------------------------------
// In-place EMA transform of proto sums -> new protos
__global__ __launch_bounds__(256) void ema_proto_kernel(
    const float* __restrict__ dproto, const float* __restrict__ sproto,
    const float* __restrict__ sum_w, const float* __restrict__ cnt,
    float* __restrict__ outd, float* __restrict__ outs)
{
  const size_t nd = (size_t)UBD * RD;          // 8388608
  const size_t total = nd + (size_t)UBD * SD;  // 12582912
  for (size_t i = (size_t)blockIdx.x * 256 + threadIdx.x; i < total;
       i += (size_t)gridDim.x * 256) {
    if (i < nd) {
      const int cell = (int)(i >> 9);
      const float c = cnt[cell];
      float v;
      if (c > 0.f) {
        const float cs = fmaxf(sum_w[cell], 1e-6f);
        v = DECAY * dproto[i] + (1.f - DECAY) * (outd[i] / cs);
      } else v = dproto[i];
      outd[i] = v;
    } else {
      const size_t j = i - nd;
      const int cell = (int)(j >> 8);
      const float c = cnt[cell];
      float v;
      if (c > 0.f) {
        const float cs = fmaxf(sum_w[cell], 1e-6f);
        v = DECAY * sproto[j] + (1.f - DECAY) * (outs[j] / cs);
      } else v = sproto[j];
      outs[j] = v;
    }
  }
}

// ---------------------------------------------------------------------------
__global__ __launch_bounds__(256) void ema_small_kernel(
    const float* __restrict__ ema, const float* __restrict__ usage,
    const float* __restrict__ sum_w, const float* __restrict__ cnt,
    float* __restrict__ out_ec, float* __restrict__ out_us)
{
  const int i = blockIdx.x * 256 + threadIdx.x;
  if (i < UBD) {
    const float c = cnt[i];
    const float cm = sum_w[i] / fmaxf(c, 1.f);
    out_ec[i] = (c > 0.f) ? DECAY * ema[i] + (1.f - DECAY) * cm : ema[i];
    out_us[i] = usage[i] + c;
  }
}

// ---------------------------------------------------------------------------
// write_rate, usage_fraction, usage_entropy (single block)
__global__ __launch_bounds__(256) void stats_kernel(
    const float* __restrict__ cnt, const float* __restrict__ new_us,
    float* __restrict__ out_scalars)
{
  const int t = threadIdx.x;
  __shared__ float r1[256], r2[256], r3[256];
  float scnt = 0.f, snz = 0.f, sus = 0.f;
  for (int i = t; i < UBD; i += 256) {
    const float c = cnt[i]; scnt += c;
    const float u = new_us[i];
    if (u > 0.f) snz += 1.f;
    sus += u;
  }
  r1[t] = scnt; r2[t] = snz; r3[t] = sus;
  __syncthreads();
  for (int s = 128; s > 0; s >>= 1) {
    if (t < s) { r1[t] += r1[t + s]; r2[t] += r2[t + s]; r3[t] += r3[t + s]; }
    __syncthreads();
  }
  const float total_cnt = r1[0], total_nz = r2[0], total_us = r3[0];
  __syncthreads();
  const float S = fmaxf(total_us, 1e-6f);
  float ent = 0.f;
  for (int i = t; i < UBD; i += 256) {
    const float d = new_us[i] / S;
    ent += d * logf(d + 1e-6f);
  }
  r1[t] = ent;
  __syncthreads();
  for (int s = 128; s > 0; s >>= 1) {
    if (t < s) { r1[t] += r1[t + s]; }
    __syncthreads();
  }
  if (t == 0) {
    out_scalars[0] = total_cnt / (float)NR;
    out_scalars[1] = total_nz / (float)UBD;
    out_scalars[2] = -r1[0] / 9.70406053f;   // ln(16384)
  }
}

// ---------------------------------------------------------------------------
extern "C" void kernel_launch(void* const* d_in, const int* in_sizes, int n_in,
                              void* d_out, int out_size, void* d_ws, size_t ws_size,
                              hipStream_t stream)
{
  const float* q_u    = (const float*)d_in[0];
  const float* q_b    = (const float*)d_in[1];
  const float* q_sig  = (const float*)d_in[2];
  const float* dtg    = (const float*)d_in[3];
  const unsigned char* wm = (const unsigned char*)d_in[4];
  const float* dproto = (const float*)d_in[5];
  const float* sproto = (const float*)d_in[6];
  const float* ema    = (const float*)d_in[7];
  const float* usage  = (const float*)d_in[8];
  float* out = (float*)d_out;

  float* wsf = (float*)d_ws;
  int*   wsi = (int*)d_ws;
  int*   flag     = wsi;                       // [16]
  float* denom    = wsf + 16;                  // [4096]
  float* base_raw = wsf + 16 + 4096;           // [4096]
  float* wgtb     = wsf + 16 + 8192;           // [4096]
  int*   cellid   = wsi + 16 + 12288;          // [4096]
  float* mrow     = wsf + 16 + 16384;          // [4096]
  float* sum_w    = wsf + 16 + 20480;          // [16384]
  float* cnt      = wsf + 16 + 20480 + 16384;  // [16384]

  // zero accumulators (sum_w+cnt contiguous; NDP+NSP contiguous in d_out)
  hipMemsetAsync(sum_w, 0, 2u * UBD * sizeof(float), stream);
  hipMemsetAsync(out + OFF_NDP, 0, (size_t)UBD * (RD + SD) * sizeof(float), stream);

  detect_mask_kernel<<<1, 64, 0, stream>>>(wm, flag);
  row_prep_kernel<<<NR, 256, 0, stream>>>(q_u, q_b, usage, ema, wm, flag,
                                          denom, base_raw, wgtb, cellid, mrow);
  retrieve_gemm_kernel<<<dim3(NR / TM, 12), 256, 0, stream>>>(
      q_u, q_b, usage, dproto, sproto, denom, out);
  conf_kernel<<<NR, 256, 0, stream>>>(q_sig, out, denom, base_raw, out + OFF_MCONF);
  scatter_kernel<<<NR, 256, 0, stream>>>(dtg, q_sig, wgtb, cellid, mrow,
                                         out + OFF_NDP, out + OFF_NSP, sum_w, cnt);
  ema_proto_kernel<<<4096, 256, 0, stream>>>(dproto, sproto, sum_w, cnt,
                                             out + OFF_NDP, out + OFF_NSP);
  ema_small_kernel<<<UBD / 256, 256, 0, stream>>>(ema, usage, sum_w, cnt,
                                                  out + OFF_NEC, out + OFF_NUS);
  stats_kernel<<<1, 256, 0, stream>>>(cnt, out + OFF_NUS, out + OFF_SCAL);
}

// Round 2
// 522.975 us; speedup vs baseline: 3.6512x; 3.6512x over previous
//
#include <hip/hip_runtime.h>
#include <hip/hip_bf16.h>
#include <math.h>

#define NR 4096
#define UD 64
#define BD 256
#define SD 256
#define RD 512
#define UBD 16384
#define DECAY 0.99f

typedef unsigned short ushort_t;
typedef __attribute__((ext_vector_type(8))) short short8;
typedef __attribute__((ext_vector_type(4))) float f32x4;

// output offsets (in floats), concatenated in reference return order
#define OFF_MDR   0ull          // memory_delta_rule   [4096,512]
#define OFF_MSIG  2097152ull    // memory_signature    [4096,256]
#define OFF_MCONF 3145728ull    // memory_conf         [4096,1]
#define OFF_NDP   3149824ull    // new_delta_proto     [64,256,512]
#define OFF_NSP   11538432ull   // new_signature_proto [64,256,256]
#define OFF_NEC   15732736ull   // new_ema_conf        [64,256]
#define OFF_NUS   15749120ull   // new_usage           [64,256]
#define OFF_SCAL  15765504ull   // write_rate, usage_fraction, usage_entropy

static __device__ __forceinline__ ushort_t f2bf(float x) {
  __hip_bfloat16 h = __float2bfloat16(x);   // RNE; compiler packs pairs well
  ushort_t u;
  __builtin_memcpy(&u, &h, 2);
  return u;
}

// ---------------------------------------------------------------------------
// Detect how write_mask (jax bool) was delivered: int32 (2), float32 (1), byte (0)
__global__ void detect_mask_kernel(const unsigned char* __restrict__ wm,
                                   int* __restrict__ flag)
{
  if (threadIdx.x != 0 || blockIdx.x != 0) return;
  const int*   wi = (const int*)wm;
  const float* wf = (const float*)wm;
  bool is_i32 = true, is_f32 = true;
  for (int i = 0; i < 16; ++i) {
    int v = wi[i];
    if (v != 0 && v != 1) is_i32 = false;
    float f = wf[i];
    if (f != 0.f && f != 1.f) is_f32 = false;
  }
  *flag = is_i32 ? 2 : (is_f32 ? 1 : 0);
}

// ---------------------------------------------------------------------------
// Per-row: denom, unnormalized base_conf, argmax(q_u), argmax(q_b), wgt, cell, m
__global__ __launch_bounds__(256) void row_prep_kernel(
    const float* __restrict__ q_u, const float* __restrict__ q_b,
    const float* __restrict__ usage, const float* __restrict__ ema,
    const unsigned char* __restrict__ wm, const int* __restrict__ flag,
    float* __restrict__ denom, float* __restrict__ base_raw,
    float* __restrict__ wgt, int* __restrict__ cellid, float* __restrict__ mrow)
{
  const int n = blockIdx.x;
  const int t = threadIdx.x;
  __shared__ float s_qu[UD];
  __shared__ float r1[256];
  __shared__ float r2[256];
  __shared__ int   ri[256];
  if (t < UD) s_qu[t] = q_u[(size_t)n * UD + t];
  __syncthreads();
  const float qb = q_b[(size_t)n * BD + t];
  float accd = 0.f, accc = 0.f;
  #pragma unroll 4
  for (int u = 0; u < UD; ++u) {
    const int idx = u * BD + t;
    if (usage[idx] > 0.f) {
      const float qu = s_qu[u];
      accd += qu;
      accc += qu * ema[idx];
    }
  }
  accd *= qb; accc *= qb;
  r1[t] = accd; r2[t] = accc;
  __syncthreads();
  for (int s = 128; s > 0; s >>= 1) {
    if (t < s) { r1[t] += r1[t + s]; r2[t] += r2[t + s]; }
    __syncthreads();
  }
  const float dsum = r1[0];
  const float csum = r2[0];
  __syncthreads();
  // argmax over q_b (first-index tie-break)
  r1[t] = qb; ri[t] = t;
  __syncthreads();
  for (int s = 128; s > 0; s >>= 1) {
    if (t < s) {
      float v2 = r1[t + s]; int i2 = ri[t + s];
      if (v2 > r1[t] || (v2 == r1[t] && i2 < ri[t])) { r1[t] = v2; ri[t] = i2; }
    }
    __syncthreads();
  }
  const float bmax = r1[0]; const int bidx = ri[0];
  __syncthreads();
  // argmax over q_u
  r1[t] = (t < UD) ? s_qu[t] : -1e30f; ri[t] = t;
  __syncthreads();
  for (int s = 128; s > 0; s >>= 1) {
    if (t < s) {
      float v2 = r1[t + s]; int i2 = ri[t + s];
      if (v2 > r1[t] || (v2 == r1[t] && i2 < ri[t])) { r1[t] = v2; ri[t] = i2; }
    }
    __syncthreads();
  }
  if (t == 0) {
    const float umax = r1[0]; const int uidx = ri[0];
    const int fm = *flag;
    float m;
    if (fm == 2)      m = (((const int*)wm)[n]   != 0)   ? 1.f : 0.f;
    else if (fm == 1) m = (((const float*)wm)[n] != 0.f) ? 1.f : 0.f;
    else              m = (wm[n] != 0) ? 1.f : 0.f;
    denom[n]    = dsum;
    base_raw[n] = csum;
    wgt[n]      = umax * bmax * m;
    cellid[n]   = uidx * BD + bidx;
    mrow[n]     = m;
  }
}

// ---------------------------------------------------------------------------
// Precompute masked, TRANSPOSED bf16 proto: PT[c][k], c in [0,768), k in [0,16384)
//   c < 512: delta_rule_proto col c; c >= 512: signature_proto col c-512
//   masked by (usage[k] > 0)
__global__ __launch_bounds__(256) void transpose_mask_kernel(
    const float* __restrict__ dproto, const float* __restrict__ sproto,
    const float* __restrict__ usage, ushort_t* __restrict__ PT)
{
  __shared__ ushort_t s[64][66];
  const int k0 = blockIdx.x * 64;
  const int rblk = blockIdx.y;       // 0..11
  const float* src; int ld; int c0s;
  if (rblk < 8) { src = dproto; ld = RD; c0s = rblk * 64; }
  else          { src = sproto; ld = SD; c0s = (rblk - 8) * 64; }
  const int tid = threadIdx.x;
  const int kl = tid >> 4;           // 0..15
  const int rl = (tid & 15) * 4;
  #pragma unroll
  for (int i = 0; i < 4; ++i) {
    const int k = kl + i * 16;
    const bool valid = usage[k0 + k] > 0.f;
    const float4 v = *(const float4*)(src + (size_t)(k0 + k) * ld + c0s + rl);
    s[k][rl + 0] = valid ? f2bf(v.x) : (ushort_t)0;
    s[k][rl + 1] = valid ? f2bf(v.y) : (ushort_t)0;
    s[k][rl + 2] = valid ? f2bf(v.z) : (ushort_t)0;
    s[k][rl + 3] = valid ? f2bf(v.w) : (ushort_t)0;
  }
  __syncthreads();
  const int rl2 = tid >> 4;
  const int kl2 = (tid & 15) * 4;
  #pragma unroll
  for (int i = 0; i < 4; ++i) {
    const int r = rl2 + i * 16;
    ushort_t tmp[4] = { s[kl2 + 0][r], s[kl2 + 1][r], s[kl2 + 2][r], s[kl2 + 3][r] };
    uint2 w; __builtin_memcpy(&w, tmp, 8);
    *(uint2*)(PT + (size_t)(rblk * 64 + r) * UBD + k0 + kl2) = w;
  }
}

// ---------------------------------------------------------------------------
// MFMA retrieve GEMM: Craw[n,c] += sum_k bf16(qu[n,k>>8]*qb[n,k&255]) * PT[c,k]
// 128x128 tile, BK=64, 4 waves (2x2) each owning 64x64; split-K x4 with f32
// atomicAdd into the zeroed MDR/MSIG output regions. XOR-swizzled LDS
// (byte ^= (row&7)<<4) makes frag ds_read_b128 2-way (free).
#define GBK 64

__global__ __launch_bounds__(256) void mfma_gemm_kernel(
    const float* __restrict__ q_u, const float* __restrict__ q_b,
    const ushort_t* __restrict__ PT, float* __restrict__ out)
{
  __shared__ ushort_t sA[128 * 64];   // [row][k] bf16, swizzled
  __shared__ ushort_t sB[128 * 64];   // [col][k] bf16, swizzled
  const int tid = threadIdx.x;
  const int n0 = blockIdx.x * 128;
  const int kbeg = blockIdx.z * (UBD / 4);
  const int kend = kbeg + UBD / 4;

  float* obase; int ldO; int cc0;
  if (blockIdx.y < 4) { obase = out + OFF_MDR;  ldO = RD; cc0 = blockIdx.y * 128; }
  else                { obase = out + OFF_MSIG; ldO = SD; cc0 = (blockIdx.y - 4) * 128; }
  const int c0 = blockIdx.y * 128;    // global PT row (col index 0..767)

  const int srow = tid & 127;         // staging row (A: n-row, B: col)
  const int skh  = tid >> 7;          // 0/1 -> which 32-k half
  const uint sw  = (uint)((srow & 7) << 4);
  const uint sbase = (uint)(srow * 128 + skh * 64);

  const int wid = tid >> 6, lane = tid & 63;
  const int wr = (wid >> 1) * 64, wc = (wid & 1) * 64;
  const int fr = lane & 15;
  const int fk = (lane >> 4) * 16;    // frag k byte offset (8 bf16)

  f32x4 acc[4][4];
  #pragma unroll
  for (int m = 0; m < 4; ++m)
    #pragma unroll
    for (int nn = 0; nn < 4; ++nn)
      acc[m][nn] = (f32x4){0.f, 0.f, 0.f, 0.f};

  for (int k0 = kbeg; k0 < kend; k0 += GBK) {
    const int u  = k0 >> 8;
    const int b0 = k0 & 255;
    // ---- generate A tile: bf16(qu * qb), 32 elems/thread, 4x ds_write_b128
    {
      const float qu = q_u[(size_t)(n0 + srow) * UD + u];
      const float* qbp = q_b + (size_t)(n0 + srow) * BD + b0 + skh * 32;
      #pragma unroll
      for (int c = 0; c < 4; ++c) {
        const float4 v0 = *(const float4*)(qbp + c * 8);
        const float4 v1 = *(const float4*)(qbp + c * 8 + 4);
        short8 h;
        h[0] = (short)f2bf(v0.x * qu); h[1] = (short)f2bf(v0.y * qu);
        h[2] = (short)f2bf(v0.z * qu); h[3] = (short)f2bf(v0.w * qu);
        h[4] = (short)f2bf(v1.x * qu); h[5] = (short)f2bf(v1.y * qu);
        h[6] = (short)f2bf(v1.z * qu); h[7] = (short)f2bf(v1.w * qu);
        *(short8*)((char*)sA + ((sbase + c * 16) ^ sw)) = h;
      }
    }
    // ---- stage B tile from PT (already bf16+masked), 4x 16B
    {
      const ushort_t* src = PT + (size_t)(c0 + srow) * UBD + k0 + skh * 32;
      #pragma unroll
      for (int c = 0; c < 4; ++c) {
        const int4 v = *(const int4*)(src + c * 8);
        *(int4*)((char*)sB + ((sbase + c * 16) ^ sw)) = v;
      }
    }
    __syncthreads();
    #pragma unroll
    for (int ks = 0; ks < 2; ++ks) {
      short8 av[4], bv[4];
      #pragma unroll
      for (int m = 0; m < 4; ++m) {
        const int row = wr + m * 16 + fr;
        av[m] = *(const short8*)((const char*)sA +
                 ((uint)(row * 128 + ks * 64 + fk) ^ (uint)((row & 7) << 4)));
      }
      #pragma unroll
      for (int nn = 0; nn < 4; ++nn) {
        const int row = wc + nn * 16 + fr;
        bv[nn] = *(const short8*)((const char*)sB +
                 ((uint)(row * 128 + ks * 64 + fk) ^ (uint)((row & 7) << 4)));
      }
      #pragma unroll
      for (int m = 0; m < 4; ++m)
        #pragma unroll
        for (int nn = 0; nn < 4; ++nn)
          acc[m][nn] = __builtin_amdgcn_mfma_f32_16x16x32_bf16(av[m], bv[nn],
                                                               acc[m][nn], 0, 0, 0);
    }
    __syncthreads();
  }
  // ---- epilogue: atomic accumulate raw sums (scaled later by 1/denom)
  const int orow = (lane >> 4) * 4;
  #pragma unroll
  for (int m = 0; m < 4; ++m) {
    #pragma unroll
    for (int nn = 0; nn < 4; ++nn) {
      const int c = cc0 + wc + nn * 16 + fr;
      #pragma unroll
      for (int j = 0; j < 4; ++j) {
        const int r = n0 + wr + m * 16 + orow + j;
        atomicAdd(obase + (size_t)r * ldO + c, acc[m][nn][j]);
      }
    }
  }
}

// ---------------------------------------------------------------------------
// Scale raw GEMM sums by 1/denom in place; fuse memory_conf (cosine) computation
__global__ __launch_bounds__(256) void epilogue_kernel(
    const float* __restrict__ q_sigma, const float* __restrict__ denom,
    const float* __restrict__ base_raw, float* __restrict__ out)
{
  const int n = blockIdx.x;
  const int t = threadIdx.x;
  __shared__ float r1[256], r2[256], r3[256];
  const float d = denom[n];
  const float scale = (d > 0.f) ? (1.f / fmaxf(d, 1e-6f)) : 0.f;
  float* mdr = out + OFF_MDR + (size_t)n * RD;
  mdr[t]       *= scale;
  mdr[t + 256] *= scale;
  float* msig = out + OFF_MSIG + (size_t)n * SD;
  const float s = msig[t] * scale;
  msig[t] = s;
  const float a = q_sigma[(size_t)n * SD + t];
  const float b = s + 1e-6f;
  r1[t] = a * a; r2[t] = b * b; r3[t] = a * b;
  __syncthreads();
  for (int st = 128; st > 0; st >>= 1) {
    if (t < st) { r1[t] += r1[t + st]; r2[t] += r2[t + st]; r3[t] += r3[t + st]; }
    __syncthreads();
  }
  if (t == 0) {
    const float na = fmaxf(sqrtf(r1[0]), 1e-12f);
    const float nb = fmaxf(sqrtf(r2[0]), 1e-12f);
    const float cosv = r3[0] / (na * nb);
    const float agree = 0.5f * (1.f + cosv);
    const float base = (d > 0.f) ? base_raw[n] / fmaxf(d, 1e-6f) : 0.f;
    out[OFF_MCONF + n] = fminf(fmaxf(base * agree, 0.f), 1.f);
  }
}

// ---------------------------------------------------------------------------
// Scatter segment-sums into the (zeroed) new_*_proto output regions + sum_w/cnt
__global__ __launch_bounds__(256) void scatter_kernel(
    const float* __restrict__ dtarget, const float* __restrict__ q_sigma,
    const float* __restrict__ wgt, const int* __restrict__ cellid,
    const float* __restrict__ mrow,
    float* __restrict__ sumd, float* __restrict__ sums,
    float* __restrict__ sum_w, float* __restrict__ cnt)
{
  const int n = blockIdx.x;
  if (mrow[n] == 0.f) return;
  const int t = threadIdx.x;
  const int c = cellid[n];
  const float w = wgt[n];
  atomicAdd(&sumd[(size_t)c * RD + t],       dtarget[(size_t)n * RD + t] * w);
  atomicAdd(&sumd[(size_t)c * RD + t + 256], dtarget[(size_t)n * RD + t + 256] * w);
  atomicAdd(&sums[(size_t)c * SD + t],       q_sigma[(size_t)n * SD + t] * w);
  if (t == 0) { atomicAdd(&sum_w[c], w); atomicAdd(&cnt[c], 1.f); }
}

// ---------------------------------------------------------------------------
// In-place EMA transform of proto sums -> new protos
__global__ __launch_bounds__(256) void ema_proto_kernel(
    const float* __restrict__ dproto, const float* __restrict__ sproto,
    const float* __restrict__ sum_w, const float* __restrict__ cnt,
    float* __restrict__ outd, float* __restrict__ outs)
{
  const size_t nd = (size_t)UBD * RD;          // 8388608
  const size_t total = nd + (size_t)UBD * SD;  // 12582912
  for (size_t i = (size_t)blockIdx.x * 256 + threadIdx.x; i < total;
       i += (size_t)gridDim.x * 256) {
    if (i < nd) {
      const int cell = (int)(i >> 9);
      const float c = cnt[cell];
      float v;
      if (c > 0.f) {
        const float cs = fmaxf(sum_w[cell], 1e-6f);
        v = DECAY * dproto[i] + (1.f - DECAY) * (outd[i] / cs);
      } else v = dproto[i];
      outd[i] = v;
    } else {
      const size_t j = i - nd;
      const int cell = (int)(j >> 8);
      const float c = cnt[cell];
      float v;
      if (c > 0.f) {
        const float cs = fmaxf(sum_w[cell], 1e-6f);
        v = DECAY * sproto[j] + (1.f - DECAY) * (outs[j] / cs);
      } else v = sproto[j];
      outs[j] = v;
    }
  }
}

// ---------------------------------------------------------------------------
__global__ __launch_bounds__(256) void ema_small_kernel(
    const float* __restrict__ ema, const float* __restrict__ usage,
    const float* __restrict__ sum_w, const float* __restrict__ cnt,
    float* __restrict__ out_ec, float* __restrict__ out_us)
{
  const int i = blockIdx.x * 256 + threadIdx.x;
  if (i < UBD) {
    const float c = cnt[i];
    const float cm = sum_w[i] / fmaxf(c, 1.f);
    out_ec[i] = (c > 0.f) ? DECAY * ema[i] + (1.f - DECAY) * cm : ema[i];
    out_us[i] = usage[i] + c;
  }
}

// ---------------------------------------------------------------------------
// write_rate, usage_fraction, usage_entropy (single block)
__global__ __launch_bounds__(256) void stats_kernel(
    const float* __restrict__ cnt, const float* __restrict__ new_us,
    float* __restrict__ out_scalars)
{
  const int t = threadIdx.x;
  __shared__ float r1[256], r2[256], r3[256];
  float scnt = 0.f, snz = 0.f, sus = 0.f;
  for (int i = t; i < UBD; i += 256) {
    const float c = cnt[i]; scnt += c;
    const float u = new_us[i];
    if (u > 0.f) snz += 1.f;
    sus += u;
  }
  r1[t] = scnt; r2[t] = snz; r3[t] = sus;
  __syncthreads();
  for (int s = 128; s > 0; s >>= 1) {
    if (t < s) { r1[t] += r1[t + s]; r2[t] += r2[t + s]; r3[t] += r3[t + s]; }
    __syncthreads();
  }
  const float total_cnt = r1[0], total_nz = r2[0], total_us = r3[0];
  __syncthreads();
  const float S = fmaxf(total_us, 1e-6f);
  float ent = 0.f;
  for (int i = t; i < UBD; i += 256) {
    const float d = new_us[i] / S;
    ent += d * logf(d + 1e-6f);
  }
  r1[t] = ent;
  __syncthreads();
  for (int s = 128; s > 0; s >>= 1) {
    if (t < s) { r1[t] += r1[t + s]; }
    __syncthreads();
  }
  if (t == 0) {
    out_scalars[0] = total_cnt / (float)NR;
    out_scalars[1] = total_nz / (float)UBD;
    out_scalars[2] = -r1[0] / 9.70406053f;   // ln(16384)
  }
}

// ---------------------------------------------------------------------------
extern "C" void kernel_launch(void* const* d_in, const int* in_sizes, int n_in,
                              void* d_out, int out_size, void* d_ws, size_t ws_size,
                              hipStream_t stream)
{
  const float* q_u    = (const float*)d_in[0];
  const float* q_b    = (const float*)d_in[1];
  const float* q_sig  = (const float*)d_in[2];
  const float* dtg    = (const float*)d_in[3];
  const unsigned char* wm = (const unsigned char*)d_in[4];
  const float* dproto = (const float*)d_in[5];
  const float* sproto = (const float*)d_in[6];
  const float* ema    = (const float*)d_in[7];
  const float* usage  = (const float*)d_in[8];
  float* out = (float*)d_out;

  float* wsf = (float*)d_ws;
  int*   wsi = (int*)d_ws;
  int*   flag     = wsi;                       // [16]
  float* denom    = wsf + 16;                  // [4096]
  float* base_raw = wsf + 16 + 4096;           // [4096]
  float* wgtb     = wsf + 16 + 8192;           // [4096]
  int*   cellid   = wsi + 16 + 12288;          // [4096]
  float* mrow     = wsf + 16 + 16384;          // [4096]
  float* sum_w    = wsf + 16 + 20480;          // [16384]
  float* cnt      = wsf + 16 + 20480 + 16384;  // [16384]

  // PT (bf16 masked transposed proto, 768x16384 = 25.2 MB) parks in the NDP
  // output region, which is not written until after the GEMM has consumed PT.
  ushort_t* PT = (ushort_t*)(out + OFF_NDP);

  transpose_mask_kernel<<<dim3(UBD / 64, 12), 256, 0, stream>>>(dproto, sproto,
                                                                usage, PT);
  // zero raw-sum targets (MDR+MSIG contiguous) and scatter accumulators
  hipMemsetAsync(out, 0, (size_t)OFF_MCONF * sizeof(float), stream);
  hipMemsetAsync(sum_w, 0, 2u * UBD * sizeof(float), stream);

  detect_mask_kernel<<<1, 64, 0, stream>>>(wm, flag);
  row_prep_kernel<<<NR, 256, 0, stream>>>(q_u, q_b, usage, ema, wm, flag,
                                          denom, base_raw, wgtb, cellid, mrow);
  mfma_gemm_kernel<<<dim3(NR / 128, 6, 4), 256, 0, stream>>>(q_u, q_b, PT, out);
  epilogue_kernel<<<NR, 256, 0, stream>>>(q_sig, denom, base_raw, out);

  // PT consumed; now zero the proto accumulator regions and run the update path
  hipMemsetAsync(out + OFF_NDP, 0, (size_t)UBD * (RD + SD) * sizeof(float), stream);
  scatter_kernel<<<NR, 256, 0, stream>>>(dtg, q_sig, wgtb, cellid, mrow,
                                         out + OFF_NDP, out + OFF_NSP, sum_w, cnt);
  ema_proto_kernel<<<4096, 256, 0, stream>>>(dproto, sproto, sum_w, cnt,
                                             out + OFF_NDP, out + OFF_NSP);
  ema_small_kernel<<<UBD / 256, 256, 0, stream>>>(ema, usage, sum_w, cnt,
                                                  out + OFF_NEC, out + OFF_NUS);
  stats_kernel<<<1, 256, 0, stream>>>(cnt, out + OFF_NUS, out + OFF_SCAL);
}

// Round 3
// 414.144 us; speedup vs baseline: 4.6106x; 1.2628x over previous
//
#include <hip/hip_runtime.h>
#include <hip/hip_bf16.h>
#include <math.h>

#define NR 4096
#define UD 64
#define BD 256
#define SD 256
#define RD 512
#define UBD 16384
#define DECAY 0.99f

typedef unsigned short ushort_t;
typedef _Float16 f16x8 __attribute__((ext_vector_type(8)));
typedef __attribute__((ext_vector_type(4))) float f32x4;

// output offsets (in floats), concatenated in reference return order
#define OFF_MDR   0ull          // memory_delta_rule   [4096,512]
#define OFF_MSIG  2097152ull    // memory_signature    [4096,256]
#define OFF_MCONF 3145728ull    // memory_conf         [4096,1]
#define OFF_NDP   3149824ull    // new_delta_proto     [64,256,512]
#define OFF_NSP   11538432ull   // new_signature_proto [64,256,256]
#define OFF_NEC   15732736ull   // new_ema_conf        [64,256]
#define OFF_NUS   15749120ull   // new_usage           [64,256]
#define OFF_SCAL  15765504ull   // write_rate, usage_fraction, usage_entropy

static __device__ __forceinline__ ushort_t f2h(float x) {
  _Float16 h = (_Float16)x;    // RNE
  ushort_t u;
  __builtin_memcpy(&u, &h, 2);
  return u;
}

static __device__ __forceinline__ void gll16(const void* g, void* l) {
  __builtin_amdgcn_global_load_lds(
      (const __attribute__((address_space(1))) unsigned int*)g,
      (__attribute__((address_space(3))) unsigned int*)l, 16, 0, 0);
}

// ---------------------------------------------------------------------------
// Detect how write_mask (jax bool) was delivered: int32 (2), float32 (1), byte (0)
__global__ void detect_mask_kernel(const unsigned char* __restrict__ wm,
                                   int* __restrict__ flag)
{
  if (threadIdx.x != 0 || blockIdx.x != 0) return;
  const int*   wi = (const int*)wm;
  const float* wf = (const float*)wm;
  bool is_i32 = true, is_f32 = true;
  for (int i = 0; i < 16; ++i) {
    int v = wi[i];
    if (v != 0 && v != 1) is_i32 = false;
    float f = wf[i];
    if (f != 0.f && f != 1.f) is_f32 = false;
  }
  *flag = is_i32 ? 2 : (is_f32 ? 1 : 0);
}

// ---------------------------------------------------------------------------
// Per-row: denom, unnormalized base_conf, argmax(q_u), argmax(q_b), wgt, cell, m
__global__ __launch_bounds__(256) void row_prep_kernel(
    const float* __restrict__ q_u, const float* __restrict__ q_b,
    const float* __restrict__ usage, const float* __restrict__ ema,
    const unsigned char* __restrict__ wm, const int* __restrict__ flag,
    float* __restrict__ denom, float* __restrict__ base_raw,
    float* __restrict__ wgt, int* __restrict__ cellid, float* __restrict__ mrow)
{
  const int n = blockIdx.x;
  const int t = threadIdx.x;
  __shared__ float s_qu[UD];
  __shared__ float r1[256];
  __shared__ float r2[256];
  __shared__ int   ri[256];
  if (t < UD) s_qu[t] = q_u[(size_t)n * UD + t];
  __syncthreads();
  const float qb = q_b[(size_t)n * BD + t];
  float accd = 0.f, accc = 0.f;
  #pragma unroll 4
  for (int u = 0; u < UD; ++u) {
    const int idx = u * BD + t;
    if (usage[idx] > 0.f) {
      const float qu = s_qu[u];
      accd += qu;
      accc += qu * ema[idx];
    }
  }
  accd *= qb; accc *= qb;
  r1[t] = accd; r2[t] = accc;
  __syncthreads();
  for (int s = 128; s > 0; s >>= 1) {
    if (t < s) { r1[t] += r1[t + s]; r2[t] += r2[t + s]; }
    __syncthreads();
  }
  const float dsum = r1[0];
  const float csum = r2[0];
  __syncthreads();
  // argmax over q_b (first-index tie-break)
  r1[t] = qb; ri[t] = t;
  __syncthreads();
  for (int s = 128; s > 0; s >>= 1) {
    if (t < s) {
      float v2 = r1[t + s]; int i2 = ri[t + s];
      if (v2 > r1[t] || (v2 == r1[t] && i2 < ri[t])) { r1[t] = v2; ri[t] = i2; }
    }
    __syncthreads();
  }
  const float bmax = r1[0]; const int bidx = ri[0];
  __syncthreads();
  // argmax over q_u
  r1[t] = (t < UD) ? s_qu[t] : -1e30f; ri[t] = t;
  __syncthreads();
  for (int s = 128; s > 0; s >>= 1) {
    if (t < s) {
      float v2 = r1[t + s]; int i2 = ri[t + s];
      if (v2 > r1[t] || (v2 == r1[t] && i2 < ri[t])) { r1[t] = v2; ri[t] = i2; }
    }
    __syncthreads();
  }
  if (t == 0) {
    const float umax = r1[0]; const int uidx = ri[0];
    const int fm = *flag;
    float m;
    if (fm == 2)      m = (((const int*)wm)[n]   != 0)   ? 1.f : 0.f;
    else if (fm == 1) m = (((const float*)wm)[n] != 0.f) ? 1.f : 0.f;
    else              m = (wm[n] != 0) ? 1.f : 0.f;
    denom[n]    = dsum;
    base_raw[n] = csum;
    wgt[n]      = umax * bmax * m;
    cellid[n]   = uidx * BD + bidx;
    mrow[n]     = m;
  }
}

// ---------------------------------------------------------------------------
// q_b -> fp16 (for register A-fragment generation in the GEMM)
__global__ __launch_bounds__(256) void qb_half_kernel(
    const float* __restrict__ qb, ushort_t* __restrict__ qb16)
{
  const int i = blockIdx.x * 256 + threadIdx.x;   // 262144 threads, 4 elems each
  const float4 v = *(const float4*)(qb + (size_t)i * 4);
  ushort_t tmp[4] = { f2h(v.x), f2h(v.y), f2h(v.z), f2h(v.w) };
  uint2 w; __builtin_memcpy(&w, tmp, 8);
  *(uint2*)(qb16 + (size_t)i * 4) = w;
}

// ---------------------------------------------------------------------------
// Precompute masked, TRANSPOSED fp16 proto: PT[c][k], c in [0,768), k in [0,16384)
__global__ __launch_bounds__(256) void transpose_mask_kernel(
    const float* __restrict__ dproto, const float* __restrict__ sproto,
    const float* __restrict__ usage, ushort_t* __restrict__ PT)
{
  __shared__ ushort_t s[64][66];
  const int k0 = blockIdx.x * 64;
  const int rblk = blockIdx.y;       // 0..11
  const float* src; int ld; int c0s;
  if (rblk < 8) { src = dproto; ld = RD; c0s = rblk * 64; }
  else          { src = sproto; ld = SD; c0s = (rblk - 8) * 64; }
  const int tid = threadIdx.x;
  const int kl = tid >> 4;           // 0..15
  const int rl = (tid & 15) * 4;
  #pragma unroll
  for (int i = 0; i < 4; ++i) {
    const int k = kl + i * 16;
    const bool valid = usage[k0 + k] > 0.f;
    const float4 v = *(const float4*)(src + (size_t)(k0 + k) * ld + c0s + rl);
    s[k][rl + 0] = valid ? f2h(v.x) : (ushort_t)0;
    s[k][rl + 1] = valid ? f2h(v.y) : (ushort_t)0;
    s[k][rl + 2] = valid ? f2h(v.z) : (ushort_t)0;
    s[k][rl + 3] = valid ? f2h(v.w) : (ushort_t)0;
  }
  __syncthreads();
  const int rl2 = tid >> 4;
  const int kl2 = (tid & 15) * 4;
  #pragma unroll
  for (int i = 0; i < 4; ++i) {
    const int r = rl2 + i * 16;
    ushort_t tmp[4] = { s[kl2 + 0][r], s[kl2 + 1][r], s[kl2 + 2][r], s[kl2 + 3][r] };
    uint2 w; __builtin_memcpy(&w, tmp, 8);
    *(uint2*)(PT + (size_t)(rblk * 64 + r) * UBD + k0 + kl2) = w;
  }
}

// ---------------------------------------------------------------------------
// MFMA retrieve GEMM (fp16): Craw[n,c] += sum_k (qu[n]*qb16[n,k&255]) * PT[c,k]
// 128x128 tile, BK=64, 4 waves (2x2), split-K x4, atomicAdd epilogue.
// A-fragments built in registers (no LDS); B staged via global_load_lds with
// pre-swizzled per-lane SOURCE + XOR-swizzled ds_read (rule 21), double-buffered,
// ONE __syncthreads per k-step.
#define GBK 64

__global__ __launch_bounds__(256, 3) void mfma_gemm_kernel(
    const float* __restrict__ q_u, const ushort_t* __restrict__ qb16,
    const ushort_t* __restrict__ PT, float* __restrict__ out)
{
  __shared__ ushort_t sB[2][128 * 64];   // [buf][col][k] fp16, swizzle via source
  const int tid = threadIdx.x;
  const int wid = tid >> 6, lane = tid & 63;
  const int n0 = blockIdx.x * 128;
  const int kbeg = blockIdx.z * (UBD / 4);
  const int kend = kbeg + UBD / 4;

  float* obase; int ldO; int cc0;
  if (blockIdx.y < 4) { obase = out + OFF_MDR;  ldO = RD; cc0 = blockIdx.y * 128; }
  else                { obase = out + OFF_MSIG; ldO = SD; cc0 = (blockIdx.y - 4) * 128; }
  const int c0 = blockIdx.y * 128;    // global PT row (col index 0..767)

  // ---- staging geometry: wave w stages sB rows [w*32, w*32+32), 4 gll x 1KB
  // LDS linear: lane -> row_local = lane>>3, chunk = lane&7.
  // Source pre-swizzle: chunk_src = (lane&7) ^ (lane>>3)  (involution w/ read XOR)
  const int srowbase = wid * 32;
  const int chunk_src = (lane & 7) ^ (lane >> 3);
  const ushort_t* gsrc0 = PT + (size_t)(c0 + srowbase + (lane >> 3)) * UBD
                             + kbeg + chunk_src * 8;

  // ---- fragment geometry
  const int wr = (wid >> 1) * 64, wc = (wid & 1) * 64;
  const int fr  = lane & 15;
  const int fke = (lane >> 4) * 8;       // A frag element offset in k
  const int fkb = (lane >> 4) * 16;      // B frag byte offset within 128B row

  // B frag LDS byte addresses (lane-constant XOR since (wc+nn*16+fr)&7 == fr&7)
  uint addrB[4][2];
  #pragma unroll
  for (int nn = 0; nn < 4; ++nn)
    #pragma unroll
    for (int ks = 0; ks < 2; ++ks)
      addrB[nn][ks] = (uint)((((wc + nn * 16 + fr) * 128) + ks * 64 + fkb)
                             ^ ((fr & 7) << 4));

  // A row bases
  const ushort_t* qbrow[4];
  const float* qurow[4];
  #pragma unroll
  for (int m = 0; m < 4; ++m) {
    const int row = n0 + wr + m * 16 + fr;
    qbrow[m] = qb16 + (size_t)row * BD;
    qurow[m] = q_u + (size_t)row * UD;
  }

  f32x4 acc[4][4];
  #pragma unroll
  for (int m = 0; m < 4; ++m)
    #pragma unroll
    for (int nn = 0; nn < 4; ++nn)
      acc[m][nn] = (f32x4){0.f, 0.f, 0.f, 0.f};

  // ---- prologue: stage buf0
  #pragma unroll
  for (int i = 0; i < 4; ++i)
    gll16(gsrc0 + (size_t)i * 8 * UBD, &sB[0][(srowbase + i * 8) * 64]);
  __syncthreads();

  // ---- main loop: outer over u (16), inner 4 k-steps of 64
  for (int k0 = kbeg; k0 < kend; k0 += 256) {
    const int u = k0 >> 8;
    f16x8 qs[4];
    #pragma unroll
    for (int m = 0; m < 4; ++m) {
      const _Float16 h = (_Float16)qurow[m][u];
      #pragma unroll
      for (int j = 0; j < 8; ++j) qs[m][j] = h;
    }
    #pragma unroll
    for (int bq = 0; bq < 4; ++bq) {
      const int kk = k0 + bq * GBK;
      const int cur = ((kk - kbeg) >> 6) & 1;
      const int b0 = bq * 64;
      // A fragment loads (16B each, L1/L2-served)
      f16x8 aa[4][2];
      #pragma unroll
      for (int m = 0; m < 4; ++m)
        #pragma unroll
        for (int ks = 0; ks < 2; ++ks)
          aa[m][ks] = *(const f16x8*)(qbrow[m] + b0 + ks * 32 + fke);
      // issue next-tile B stage (async; drained by the syncthreads below)
      const int kn = kk + GBK;
      if (kn < kend) {
        const ushort_t* gs = gsrc0 + (kn - kbeg);
        #pragma unroll
        for (int i = 0; i < 4; ++i)
          gll16(gs + (size_t)i * 8 * UBD, &sB[cur ^ 1][(srowbase + i * 8) * 64]);
      }
      // A frags: packed fp16 multiply
      f16x8 av[4][2];
      #pragma unroll
      for (int m = 0; m < 4; ++m)
        #pragma unroll
        for (int ks = 0; ks < 2; ++ks)
          av[m][ks] = aa[m][ks] * qs[m];
      // B frags from LDS + MFMA
      const char* sb = (const char*)&sB[cur][0];
      #pragma unroll
      for (int ks = 0; ks < 2; ++ks) {
        f16x8 bv[4];
        #pragma unroll
        for (int nn = 0; nn < 4; ++nn)
          bv[nn] = *(const f16x8*)(sb + addrB[nn][ks]);
        #pragma unroll
        for (int m = 0; m < 4; ++m)
          #pragma unroll
          for (int nn = 0; nn < 4; ++nn)
            acc[m][nn] = __builtin_amdgcn_mfma_f32_16x16x32_f16(av[m][ks], bv[nn],
                                                                acc[m][nn], 0, 0, 0);
      }
      __syncthreads();
    }
  }
  // ---- epilogue: atomic accumulate raw sums (scaled later by 1/denom)
  const int orow = (lane >> 4) * 4;
  #pragma unroll
  for (int m = 0; m < 4; ++m) {
    #pragma unroll
    for (int nn = 0; nn < 4; ++nn) {
      const int c = cc0 + wc + nn * 16 + fr;
      #pragma unroll
      for (int j = 0; j < 4; ++j) {
        const int r = n0 + wr + m * 16 + orow + j;
        atomicAdd(obase + (size_t)r * ldO + c, acc[m][nn][j]);
      }
    }
  }
}

// ---------------------------------------------------------------------------
// Scale raw GEMM sums by 1/denom in place; fuse memory_conf (cosine) computation
__global__ __launch_bounds__(256) void epilogue_kernel(
    const float* __restrict__ q_sigma, const float* __restrict__ denom,
    const float* __restrict__ base_raw, float* __restrict__ out)
{
  const int n = blockIdx.x;
  const int t = threadIdx.x;
  __shared__ float r1[256], r2[256], r3[256];
  const float d = denom[n];
  const float scale = (d > 0.f) ? (1.f / fmaxf(d, 1e-6f)) : 0.f;
  float* mdr = out + OFF_MDR + (size_t)n * RD;
  mdr[t]       *= scale;
  mdr[t + 256] *= scale;
  float* msig = out + OFF_MSIG + (size_t)n * SD;
  const float s = msig[t] * scale;
  msig[t] = s;
  const float a = q_sigma[(size_t)n * SD + t];
  const float b = s + 1e-6f;
  r1[t] = a * a; r2[t] = b * b; r3[t] = a * b;
  __syncthreads();
  for (int st = 128; st > 0; st >>= 1) {
    if (t < st) { r1[t] += r1[t + st]; r2[t] += r2[t + st]; r3[t] += r3[t + st]; }
    __syncthreads();
  }
  if (t == 0) {
    const float na = fmaxf(sqrtf(r1[0]), 1e-12f);
    const float nb = fmaxf(sqrtf(r2[0]), 1e-12f);
    const float cosv = r3[0] / (na * nb);
    const float agree = 0.5f * (1.f + cosv);
    const float base = (d > 0.f) ? base_raw[n] / fmaxf(d, 1e-6f) : 0.f;
    out[OFF_MCONF + n] = fminf(fmaxf(base * agree, 0.f), 1.f);
  }
}

// ---------------------------------------------------------------------------
// Scatter segment-sums into the (zeroed) new_*_proto output regions + sum_w/cnt
__global__ __launch_bounds__(256) void scatter_kernel(
    const float* __restrict__ dtarget, const float* __restrict__ q_sigma,
    const float* __restrict__ wgt, const int* __restrict__ cellid,
    const float* __restrict__ mrow,
    float* __restrict__ sumd, float* __restrict__ sums,
    float* __restrict__ sum_w, float* __restrict__ cnt)
{
  const int n = blockIdx.x;
  if (mrow[n] == 0.f) return;
  const int t = threadIdx.x;
  const int c = cellid[n];
  const float w = wgt[n];
  atomicAdd(&sumd[(size_t)c * RD + t],       dtarget[(size_t)n * RD + t] * w);
  atomicAdd(&sumd[(size_t)c * RD + t + 256], dtarget[(size_t)n * RD + t + 256] * w);
  atomicAdd(&sums[(size_t)c * SD + t],       q_sigma[(size_t)n * SD + t] * w);
  if (t == 0) { atomicAdd(&sum_w[c], w); atomicAdd(&cnt[c], 1.f); }
}

// ---------------------------------------------------------------------------
// In-place EMA transform of proto sums -> new protos
__global__ __launch_bounds__(256) void ema_proto_kernel(
    const float* __restrict__ dproto, const float* __restrict__ sproto,
    const float* __restrict__ sum_w, const float* __restrict__ cnt,
    float* __restrict__ outd, float* __restrict__ outs)
{
  const size_t nd = (size_t)UBD * RD;          // 8388608
  const size_t total = nd + (size_t)UBD * SD;  // 12582912
  for (size_t i = (size_t)blockIdx.x * 256 + threadIdx.x; i < total;
       i += (size_t)gridDim.x * 256) {
    if (i < nd) {
      const int cell = (int)(i >> 9);
      const float c = cnt[cell];
      float v;
      if (c > 0.f) {
        const float cs = fmaxf(sum_w[cell], 1e-6f);
        v = DECAY * dproto[i] + (1.f - DECAY) * (outd[i] / cs);
      } else v = dproto[i];
      outd[i] = v;
    } else {
      const size_t j = i - nd;
      const int cell = (int)(j >> 8);
      const float c = cnt[cell];
      float v;
      if (c > 0.f) {
        const float cs = fmaxf(sum_w[cell], 1e-6f);
        v = DECAY * sproto[j] + (1.f - DECAY) * (outs[j] / cs);
      } else v = sproto[j];
      outs[j] = v;
    }
  }
}

// ---------------------------------------------------------------------------
__global__ __launch_bounds__(256) void ema_small_kernel(
    const float* __restrict__ ema, const float* __restrict__ usage,
    const float* __restrict__ sum_w, const float* __restrict__ cnt,
    float* __restrict__ out_ec, float* __restrict__ out_us)
{
  const int i = blockIdx.x * 256 + threadIdx.x;
  if (i < UBD) {
    const float c = cnt[i];
    const float cm = sum_w[i] / fmaxf(c, 1.f);
    out_ec[i] = (c > 0.f) ? DECAY * ema[i] + (1.f - DECAY) * cm : ema[i];
    out_us[i] = usage[i] + c;
  }
}

// ---------------------------------------------------------------------------
// write_rate, usage_fraction, usage_entropy (single block)
__global__ __launch_bounds__(256) void stats_kernel(
    const float* __restrict__ cnt, const float* __restrict__ new_us,
    float* __restrict__ out_scalars)
{
  const int t = threadIdx.x;
  __shared__ float r1[256], r2[256], r3[256];
  float scnt = 0.f, snz = 0.f, sus = 0.f;
  for (int i = t; i < UBD; i += 256) {
    const float c = cnt[i]; scnt += c;
    const float u = new_us[i];
    if (u > 0.f) snz += 1.f;
    sus += u;
  }
  r1[t] = scnt; r2[t] = snz; r3[t] = sus;
  __syncthreads();
  for (int s = 128; s > 0; s >>= 1) {
    if (t < s) { r1[t] += r1[t + s]; r2[t] += r2[t + s]; r3[t] += r3[t + s]; }
    __syncthreads();
  }
  const float total_cnt = r1[0], total_nz = r2[0], total_us = r3[0];
  __syncthreads();
  const float S = fmaxf(total_us, 1e-6f);
  float ent = 0.f;
  for (int i = t; i < UBD; i += 256) {
    const float d = new_us[i] / S;
    ent += d * logf(d + 1e-6f);
  }
  r1[t] = ent;
  __syncthreads();
  for (int s = 128; s > 0; s >>= 1) {
    if (t < s) { r1[t] += r1[t + s]; }
    __syncthreads();
  }
  if (t == 0) {
    out_scalars[0] = total_cnt / (float)NR;
    out_scalars[1] = total_nz / (float)UBD;
    out_scalars[2] = -r1[0] / 9.70406053f;   // ln(16384)
  }
}

// ---------------------------------------------------------------------------
extern "C" void kernel_launch(void* const* d_in, const int* in_sizes, int n_in,
                              void* d_out, int out_size, void* d_ws, size_t ws_size,
                              hipStream_t stream)
{
  const float* q_u    = (const float*)d_in[0];
  const float* q_b    = (const float*)d_in[1];
  const float* q_sig  = (const float*)d_in[2];
  const float* dtg    = (const float*)d_in[3];
  const unsigned char* wm = (const unsigned char*)d_in[4];
  const float* dproto = (const float*)d_in[5];
  const float* sproto = (const float*)d_in[6];
  const float* ema    = (const float*)d_in[7];
  const float* usage  = (const float*)d_in[8];
  float* out = (float*)d_out;

  float* wsf = (float*)d_ws;
  int*   wsi = (int*)d_ws;
  int*   flag     = wsi;                       // [16]
  float* denom    = wsf + 16;                  // [4096]
  float* base_raw = wsf + 16 + 4096;           // [4096]
  float* wgtb     = wsf + 16 + 8192;           // [4096]
  int*   cellid   = wsi + 16 + 12288;          // [4096]
  float* mrow     = wsf + 16 + 16384;          // [4096]
  float* sum_w    = wsf + 16 + 20480;          // [16384]
  float* cnt      = wsf + 16 + 20480 + 16384;  // [16384]

  // PT (fp16 masked transposed proto, 768x16384 = 25.2 MB) and qb16 (2 MB)
  // park in the NDP output region, which is rewritten only after the GEMM.
  ushort_t* PT   = (ushort_t*)(out + OFF_NDP);
  ushort_t* qb16 = PT + (size_t)768 * UBD;

  qb_half_kernel<<<(NR * BD / 4) / 256, 256, 0, stream>>>(q_b, qb16);
  transpose_mask_kernel<<<dim3(UBD / 64, 12), 256, 0, stream>>>(dproto, sproto,
                                                                usage, PT);
  // zero raw-sum targets (MDR+MSIG contiguous) and scatter accumulators
  hipMemsetAsync(out, 0, (size_t)OFF_MCONF * sizeof(float), stream);
  hipMemsetAsync(sum_w, 0, 2u * UBD * sizeof(float), stream);

  detect_mask_kernel<<<1, 64, 0, stream>>>(wm, flag);
  row_prep_kernel<<<NR, 256, 0, stream>>>(q_u, q_b, usage, ema, wm, flag,
                                          denom, base_raw, wgtb, cellid, mrow);
  mfma_gemm_kernel<<<dim3(NR / 128, 6, 4), 256, 0, stream>>>(q_u, qb16, PT, out);
  epilogue_kernel<<<NR, 256, 0, stream>>>(q_sig, denom, base_raw, out);

  // PT/qb16 consumed; now zero the proto accumulator regions and run updates
  hipMemsetAsync(out + OFF_NDP, 0, (size_t)UBD * (RD + SD) * sizeof(float), stream);
  scatter_kernel<<<NR, 256, 0, stream>>>(dtg, q_sig, wgtb, cellid, mrow,
                                         out + OFF_NDP, out + OFF_NSP, sum_w, cnt);
  ema_proto_kernel<<<4096, 256, 0, stream>>>(dproto, sproto, sum_w, cnt,
                                             out + OFF_NDP, out + OFF_NSP);
  ema_small_kernel<<<UBD / 256, 256, 0, stream>>>(ema, usage, sum_w, cnt,
                                                  out + OFF_NEC, out + OFF_NUS);
  stats_kernel<<<1, 256, 0, stream>>>(cnt, out + OFF_NUS, out + OFF_SCAL);
}